// Round 6
// baseline (183.499 us; speedup 1.0000x reference)
//
#include <hip/hip_runtime.h>

// Causal MHSA: B=2, T=2048, C=1024, H=16, Dh=64.
// prep -> QKV GEMM -> flash attn (S^T orientation) -> out GEMM.
//
// R17 = R16 with COUNTED VMCNT at tile boundaries (T4, m218). R13/R14/R16
// benched identical (43us, MfmaUtil 21%) across three different intra-tile
// sync spellings -> the shared tile-end __syncthreads() (vmcnt(0) drain
// once per K-tile) was the bottleneck all along: "8-phase with drain0 ==
// 1-phase" (m218; m233: the flush is ~72% of critical path; 1 block/CU so
// nothing hides it). New schedule: stage for tile t+2 is issued at END of
// tile t into the buffer tile t just finished reading (post-barrier ->
// WAR-safe block-wide); boundary wait is s_waitcnt vmcnt(8) (oldest 8 =
// next tile's buffer, issued a full tile earlier) + s_barrier. vmcnt never
// drains to 0 in the main loop; single vmcnt(0) at prologue and tile-14
// ramp-down. Distinct LDS objects As0/As1/Bs0/Bs1 kept from R16.
// Fat-granule XOR swizzle from R10. attn / prep / gemm_out_k unchanged.

typedef __bf16 bf16;
typedef __attribute__((ext_vector_type(4))) __bf16 bf16x4;
typedef __attribute__((ext_vector_type(8))) __bf16 bf16x8;
typedef __attribute__((ext_vector_type(4))) float f32x4;

#define T_SEQ 2048
#define NHEAD 16
#define QSCALE 0.1803368801111244f  // log2(e)/sqrt(64)

__device__ __forceinline__ void async16(const bf16* g, const bf16* l) {
    __builtin_amdgcn_global_load_lds(
        (const __attribute__((address_space(1))) void*)g,
        (__attribute__((address_space(3))) void*)l, 16, 0, 0);
}

// ---------------- fused prep ----------------
__global__ __launch_bounds__(256) void prep(
    const float* __restrict__ x, bf16* __restrict__ xb,
    const float* __restrict__ qkv_w, bf16* __restrict__ wbT,
    const float* __restrict__ out_w, bf16* __restrict__ owbT) {
    const int bid = blockIdx.x, tid = threadIdx.x;
    if (bid < 4096) {
        int i = (bid * 256 + tid) * 4;
        float4 v = *(const float4*)(x + i);
        bf16x4 o;
        o.x = (bf16)v.x; o.y = (bf16)v.y; o.z = (bf16)v.z; o.w = (bf16)v.w;
        *(bf16x4*)(xb + i) = o;
        return;
    }
    __shared__ float tile[32][33];
    const float* in;
    bf16* out;
    int K_, N_, b;
    if (bid < 7168) { b = bid - 4096; in = qkv_w; out = wbT; K_ = 1024; N_ = 3072; }
    else            { b = bid - 7168; in = out_w; out = owbT; K_ = 1024; N_ = 1024; }
    int k0 = (b & 31) * 32, n0 = (b >> 5) * 32;
    int tx = tid & 31, ty = tid >> 5;
    for (int r = 0; r < 32; r += 8)
        tile[ty + r][tx] = in[(k0 + ty + r) * N_ + n0 + tx];
    __syncthreads();
    for (int r = 0; r < 32; r += 8)
        out[(n0 + ty + r) * K_ + k0 + tx] = (bf16)tile[tx][ty + r];
}

// ---------------- GEMM 1: qkv = x @ qkv_w + b, scatter to Q/K/Vt ----------------
// 256x256 tile, BK=64, 8-phase schedule, intrinsic barriers, counted vmcnt
// at tile boundaries (never 0 in steady state), four distinct LDS buffers.
#define PHASE_BAR __builtin_amdgcn_s_barrier()
#define WAIT_LGKM                                                         \
    asm volatile("s_waitcnt lgkmcnt(0)");                                 \
    __builtin_amdgcn_sched_barrier(0)
#define VMCNT(N)                                                          \
    do {                                                                  \
        asm volatile("s_waitcnt vmcnt(" #N ")");                          \
        __builtin_amdgcn_sched_barrier(0);                                \
    } while (0)

#define LOAD_A(MH)                                                        \
    _Pragma("unroll") for (int ii = 0; ii < 4; ii++) {                    \
        const bf16* ap = ab + ((MH) * 64 + ii * 16) * 64;                 \
        afrag[ii][0] = *(const bf16x8*)(ap + g0);                         \
        afrag[ii][1] = *(const bf16x8*)(ap + g1);                         \
    }
#define LOAD_B(NH)                                                        \
    _Pragma("unroll") for (int jj = 0; jj < 2; jj++) {                    \
        const bf16* bp = bb + ((NH) * 32 + jj * 16) * 64;                 \
        bfrag[jj][0] = *(const bf16x8*)(bp + g0);                         \
        bfrag[jj][1] = *(const bf16x8*)(bp + g1);                         \
    }
// swapped orientation (C^T per frag): D[row=n(quad*4+r)][col=m(l15)]
#define MFMA_SWAP(MH, NH)                                                 \
    __builtin_amdgcn_s_setprio(1);                                        \
    _Pragma("unroll") for (int jj = 0; jj < 2; jj++)                      \
    _Pragma("unroll") for (int ii = 0; ii < 4; ii++)                      \
    _Pragma("unroll") for (int s = 0; s < 2; s++)                         \
        acc[(MH) * 4 + ii][(NH) * 2 + jj] =                               \
            __builtin_amdgcn_mfma_f32_16x16x32_bf16(                      \
                bfrag[jj][s], afrag[ii][s],                               \
                acc[(MH) * 4 + ii][(NH) * 2 + jj], 0, 0, 0);              \
    __builtin_amdgcn_s_setprio(0);
// normal orientation: D[row=m(quad*4+r)][col=n(l15)]
#define MFMA_NORM(MH, NH)                                                 \
    __builtin_amdgcn_s_setprio(1);                                        \
    _Pragma("unroll") for (int ii = 0; ii < 4; ii++)                      \
    _Pragma("unroll") for (int jj = 0; jj < 2; jj++)                      \
    _Pragma("unroll") for (int s = 0; s < 2; s++)                         \
        acc[(MH) * 4 + ii][(NH) * 2 + jj] =                               \
            __builtin_amdgcn_mfma_f32_16x16x32_bf16(                      \
                afrag[ii][s], bfrag[jj][s],                               \
                acc[(MH) * 4 + ii][(NH) * 2 + jj], 0, 0, 0);              \
    __builtin_amdgcn_s_setprio(0);

// One K-tile reading AsR/BsR. At the end: (a) barrier proving all waves'
// AsR/BsR reads retired, (b) optionally stage tile t+2 INTO AsR/BsR,
// (c) counted vmcnt(WAITN) -> the oldest 8 loads (partner buffer, issued
// one full tile ago) are landed; the 8 just issued stay in flight,
// (d) barrier -> partner buffer valid block-wide for the next tile.
#define TILE(AsR, BsR, KNEXT, DOSTAGE, WAITN, MF)                         \
    {                                                                     \
        const bf16* ab = AsR + (wm * 128 + l15) * 64;                     \
        const bf16* bb = BsR + (wn * 64 + l15) * 64;                      \
        bf16x8 afrag[4][2], bfrag[2][2];                                  \
        LOAD_A(0);                                                        \
        LOAD_B(0);                                                        \
        PHASE_BAR;                                                        \
        WAIT_LGKM;                                                        \
        MF(0, 0);                                                         \
        PHASE_BAR;                                                        \
        LOAD_B(1);                                                        \
        PHASE_BAR;                                                        \
        WAIT_LGKM;                                                        \
        MF(0, 1);                                                         \
        PHASE_BAR;                                                        \
        LOAD_A(1);                                                        \
        PHASE_BAR;                                                        \
        WAIT_LGKM;                                                        \
        MF(1, 1);                                                         \
        PHASE_BAR;                                                        \
        LOAD_B(0);                                                        \
        PHASE_BAR;                                                        \
        WAIT_LGKM;                                                        \
        MF(1, 0);                                                         \
        PHASE_BAR;                                                        \
        if (DOSTAGE) stage2(AsR, BsR, (KNEXT));                           \
        VMCNT(WAITN);                                                     \
        PHASE_BAR;                                                        \
    }

__global__ __launch_bounds__(512, 2) void gemm_qkv(
    const bf16* __restrict__ A, const bf16* __restrict__ Bt,
    const float* __restrict__ bias,
    bf16* __restrict__ Qo, bf16* __restrict__ Ko, bf16* __restrict__ Vt) {
    __shared__ __align__(16) bf16 As0[256 * 64];
    __shared__ __align__(16) bf16 As1[256 * 64];
    __shared__ __align__(16) bf16 Bs0[256 * 64];
    __shared__ __align__(16) bf16 Bs1[256 * 64];
    const int t = threadIdx.x;
    const int lane = t & 63, wave = t >> 6;
    const int l15 = lane & 15, quad = lane >> 4;
    const int wm = wave >> 2, wn = wave & 3;  // 2 M-waves x 4 N-waves
    const int m0 = blockIdx.y * 256, n0 = blockIdx.x * 256;
    const int sec = n0 >> 10;  // block-uniform: 0=Q, 1=K, 2=V

    f32x4 acc[8][4] = {};

    // staging: per call a wave writes 8 rows x 8 granules, linear LDS dest;
    // source pre-swizzled: row&7 == l>>3 for every call, so
    // src granule = (l&7) ^ (l>>3) gives phys = logical ^ (row&7).
    const int srow8 = lane >> 3;
    const int sgr = (lane & 7) ^ srow8;
    const bf16* agbase = A + (m0 + wave * 8 + srow8) * 1024 + sgr * 8;
    const bf16* bgbase = Bt + (n0 + wave * 8 + srow8) * 1024 + sgr * 8;

    auto stage2 = [&](bf16* asbuf, bf16* bsbuf, int k0) {
        const bf16* a = agbase + k0;
        const bf16* b = bgbase + k0;
        const bf16* as = asbuf + wave * 512;
        const bf16* bs = bsbuf + wave * 512;
        async16(a, as);
        async16(a + 64 * 1024, as + 64 * 64);
        async16(a + 128 * 1024, as + 128 * 64);
        async16(a + 192 * 1024, as + 192 * 64);
        async16(b, bs);
        async16(b + 64 * 1024, bs + 64 * 64);
        async16(b + 128 * 1024, bs + 128 * 64);
        async16(b + 192 * 1024, bs + 192 * 64);
    };

    // frag reads: row = win + frag*16 + l15 -> row&7 == l15&7 (const/thread);
    // k-slice s, quad -> logical granule s*4+quad, phys ^= row&7.
    const int rsw = l15 & 7;
    const int g0 = ((0 + quad) ^ rsw) << 3;
    const int g1 = ((4 + quad) ^ rsw) << 3;

    // prologue: stage tiles 0 and 1; wait only for tile 0's 8 loads
    // (tile 1's stay in flight); align.
    stage2(As0, Bs0, 0);
    stage2(As1, Bs1, 64);
    VMCNT(8);
    PHASE_BAR;

    if (sec < 2) {
#pragma unroll 1
        for (int tt = 0; tt < 7; tt++) {
            TILE(As0, Bs0, (2 * tt + 2) * 64, true, 8, MFMA_SWAP);
            TILE(As1, Bs1, (2 * tt + 3) * 64, true, 8, MFMA_SWAP);
        }
        TILE(As0, Bs0, 0, false, 0, MFMA_SWAP);  // t=14: drain tile-15 loads
        TILE(As1, Bs1, 0, false, 0, MFMA_SWAP);  // t=15: vmcnt already 0
        bf16* dst = (sec == 0) ? Qo : Ko;
        const float sc = (sec == 0) ? QSCALE : 1.0f;
        for (int nj = 0; nj < 4; nj++) {
            int col0 = n0 + wn * 64 + nj * 16 + quad * 4;  // 4 consecutive feats
            float4 bv = *(const float4*)(bias + col0);
            int c2 = col0 & 1023, h = c2 >> 6, d0 = c2 & 63;
            for (int mi = 0; mi < 8; mi++) {
                int row = m0 + wm * 128 + mi * 16 + l15;
                int b = row >> 11, tt2 = row & 2047;
                int bh = b * NHEAD + h;
                bf16x4 o;
                o[0] = (bf16)((acc[mi][nj][0] + bv.x) * sc);
                o[1] = (bf16)((acc[mi][nj][1] + bv.y) * sc);
                o[2] = (bf16)((acc[mi][nj][2] + bv.z) * sc);
                o[3] = (bf16)((acc[mi][nj][3] + bv.w) * sc);
                *(bf16x4*)(dst + (bh * T_SEQ + tt2) * 64 + d0) = o;
            }
        }
    } else {
#pragma unroll 1
        for (int tt = 0; tt < 7; tt++) {
            TILE(As0, Bs0, (2 * tt + 2) * 64, true, 8, MFMA_NORM);
            TILE(As1, Bs1, (2 * tt + 3) * 64, true, 8, MFMA_NORM);
        }
        TILE(As0, Bs0, 0, false, 0, MFMA_NORM);
        TILE(As1, Bs1, 0, false, 0, MFMA_NORM);
        for (int nj = 0; nj < 4; nj++) {
            int col = n0 + wn * 64 + nj * 16 + l15;
            float bv = bias[col];
            int c2 = col & 1023, h = c2 >> 6, d = c2 & 63;
            for (int mi = 0; mi < 8; mi++) {
                int row0 = m0 + wm * 128 + mi * 16 + quad * 4;  // 4 consecutive t
                int b = row0 >> 11, tt0 = row0 & 2047;
                int bh = b * NHEAD + h;
                bf16x4 o;
                for (int r = 0; r < 4; r++)
                    o[r] = (bf16)(acc[mi][nj][r] + bv);
                *(bf16x4*)(Vt + (bh * 64 + d) * T_SEQ + tt0) = o;
            }
        }
    }
}

// ---------------- attention (R7, unchanged) ----------------
#define PST 80
__global__ __launch_bounds__(256, 4) void attn(
    const bf16* __restrict__ Q, const bf16* __restrict__ K,
    const bf16* __restrict__ Vt, bf16* __restrict__ AO) {
    __shared__ __align__(16) bf16 Ks[2][64 * 64];
    __shared__ __align__(16) bf16 Vs[2][64 * 64];
    __shared__ __align__(16) bf16 Pa[4][16 * PST];
    const int tid = threadIdx.x;
    const int lane = tid & 63, wave = tid >> 6;
    const int l15 = lane & 15, quad = lane >> 4;
    const int xcdr = blockIdx.x & 7;
    const int i_ = blockIdx.x >> 3;
    const int bh = (xcdr << 2) | (i_ & 3);
    const int ti = i_ >> 2;
    const int qt = (ti & 1) ? (ti >> 1) : (31 - (ti >> 1));
    const int t0w = qt * 64 + wave * 16;

    const bf16* kp = K + bh * T_SEQ * 64;
    const bf16* vp = Vt + bh * 64 * T_SEQ;
    bf16* pw = &Pa[wave][0];
    const int b_ = bh >> 4, h_ = bh & 15;

    const int sx = (quad ^ (l15 & 7)) << 3;

    const bf16* qp = Q + (bh * T_SEQ + t0w) * 64;
    bf16x8 qf0 = *(const bf16x8*)(qp + l15 * 64 + quad * 8);
    bf16x8 qf1 = *(const bf16x8*)(qp + l15 * 64 + 32 + quad * 8);

    auto stage = [&](int kb, int b) {
        for (int i = 0; i < 2; i++) {
            int row = i * 32 + (tid >> 3), p = tid & 7;
            const bf16* ksrc = kp + (kb + row) * 64 + ((p ^ (row & 7)) << 3);
            async16(ksrc, &Ks[b][i * 2048 + wave * 512]);
            const bf16* vsrc = vp + row * T_SEQ + kb + ((p ^ (row & 7)) << 3);
            async16(vsrc, &Vs[b][i * 2048 + wave * 512]);
        }
    };

    f32x4 acc[4] = {};
    float lsum = 0.0f;

    const int C = qt + 1;
    stage(0, 0);
    for (int c = 0; c < C; c++) {
        __syncthreads();
        if (c + 1 < C) stage((c + 1) * 64, (c + 1) & 1);
        const bf16* ksb = &Ks[c & 1][0];
        const bf16* vsb = &Vs[c & 1][0];
        const bool dg = (c == qt);
        const int na = dg ? (wave + 1) : 4;

        f32x4 sc[4];
        for (int n = 0; n < 4; n++) {
            if (n < na) {
                const bf16* kbase = ksb + (n * 16 + l15) * 64;
                bf16x8 kf0 = *(const bf16x8*)(kbase + sx);
                bf16x8 kf1 = *(const bf16x8*)(kbase + (sx ^ 32));
                f32x4 z = {};
                z = __builtin_amdgcn_mfma_f32_16x16x32_bf16(kf0, qf0, z, 0, 0, 0);
                z = __builtin_amdgcn_mfma_f32_16x16x32_bf16(kf1, qf1, z, 0, 0, 0);
                sc[n] = z;
            }
        }
        for (int n = 0; n < 4; n++) {
            bf16x4 pv;
            if (n < na) {
                const bool dmask = dg && (n == na - 1);
                for (int r = 0; r < 4; r++) {
                    float v = sc[n][r];
                    if (dmask && (quad * 4 + r > l15)) v = -100000.0f;
                    float e = __builtin_amdgcn_exp2f(v);
                    lsum += e;
                    pv[r] = (bf16)e;
                }
            } else {
                pv[0] = pv[1] = pv[2] = pv[3] = (bf16)0.0f;
            }
            *(bf16x4*)(pw + l15 * PST + n * 16 + quad * 4) = pv;
        }
        __builtin_amdgcn_s_waitcnt(0xC07F);
        for (int g = 0; g < 2; g++) {
            bf16x8 pf = *(const bf16x8*)(pw + l15 * PST + g * 32 + quad * 8);
            for (int j = 0; j < 4; j++) {
                const bf16* vbase = vsb + (j * 16 + l15) * 64;
                bf16x8 vf = *(const bf16x8*)(vbase + (g ? (sx ^ 32) : sx));
                acc[j] = __builtin_amdgcn_mfma_f32_16x16x32_bf16(pf, vf, acc[j], 0, 0, 0);
            }
        }
    }

    lsum += __shfl_xor(lsum, 16);
    lsum += __shfl_xor(lsum, 32);
    float linv = 1.0f / lsum;

    bf16* aop = AO + (b_ * T_SEQ + t0w) * 1024 + h_ * 64;
    for (int r = 0; r < 4; r++) {
        float lr = __shfl(linv, quad * 4 + r, 16);
        for (int j = 0; j < 4; j++)
            aop[(quad * 4 + r) * 1024 + j * 16 + l15] = (bf16)(acc[j][r] * lr);
    }
}

// ---------------- GEMM 2: out = AO @ out_w + out_b (fp32 out) ----------------
// 64x128 tile, BK=32, single-buffer two-barrier, fat-row swizzled LDS.
// 512 blocks (2/CU). C^T orientation -> float4 stores.
__global__ __launch_bounds__(256) void gemm_out_k(
    const bf16* __restrict__ A, const bf16* __restrict__ Bt,
    const float* __restrict__ bias, float* __restrict__ out) {
    __shared__ __align__(16) bf16 As[64 * 32];
    __shared__ __align__(16) bf16 Bs[128 * 32];
    const int t = threadIdx.x;
    const int lane = t & 63, wave = t >> 6;
    const int l15 = lane & 15, quad = lane >> 4;
    const int wm = wave & 1, wn = wave >> 1;
    const int m0 = blockIdx.y * 64, n0 = blockIdx.x * 128;

    f32x4 acc[4][2] = {};  // acc[j][i]: C^T (row=feature, col=t)

    const int sfat = t >> 3, sp = t & 7;
    const int slg = sp ^ (sfat & 7);
    const int smrow = sfat * 2 + (slg >> 2);
    const int skoff = (slg & 3) << 3;
    const bf16* ag = A + (m0 + smrow) * 1024 + skoff;
    const bf16* bg = Bt + (n0 + smrow) * 1024 + skoff;
    bf16* as0 = As + wave * 512;
    bf16* bs0 = Bs + wave * 512;
    bf16* bs1 = Bs + 2048 + wave * 512;

    const int foff = (l15 >> 1) * 64 + (((((l15 & 1) << 2) | quad)) ^ (l15 >> 1)) * 8;

    for (int k0 = 0; k0 < 1024; k0 += 32) {
        async16(ag + k0, as0);
        async16(bg + k0, bs0);
        async16(bg + 64 * 1024 + k0, bs1);
        __syncthreads();
        bf16x8 af[2], bfr[4];
        for (int i = 0; i < 2; i++)
            af[i] = *(const bf16x8*)(As + (wm * 32 + i * 16) * 32 + foff);
        for (int j = 0; j < 4; j++)
            bfr[j] = *(const bf16x8*)(Bs + (wn * 64 + j * 16) * 32 + foff);
        for (int j = 0; j < 4; j++)
            for (int i = 0; i < 2; i++)
                acc[j][i] = __builtin_amdgcn_mfma_f32_16x16x32_bf16(bfr[j], af[i], acc[j][i], 0, 0, 0);
        __syncthreads();
    }

    for (int j = 0; j < 4; j++) {
        int col0 = n0 + wn * 64 + j * 16 + quad * 4;
        float4 bv = *(const float4*)(bias + col0);
        for (int i = 0; i < 2; i++) {
            int row = m0 + wm * 32 + i * 16 + l15;
            float4 o;
            o.x = acc[j][i][0] + bv.x;
            o.y = acc[j][i][1] + bv.y;
            o.z = acc[j][i][2] + bv.z;
            o.w = acc[j][i][3] + bv.w;
            *(float4*)(out + row * 1024 + col0) = o;
        }
    }
}

// ---------------- launch ----------------
extern "C" void kernel_launch(void* const* d_in, const int* in_sizes, int n_in,
                              void* d_out, int out_size, void* d_ws, size_t ws_size,
                              hipStream_t stream) {
    const float* x     = (const float*)d_in[0];
    const float* qkv_w = (const float*)d_in[1];
    const float* qkv_b = (const float*)d_in[2];
    const float* out_w = (const float*)d_in[3];
    const float* out_b = (const float*)d_in[4];
    float* out = (float*)d_out;

    char* ws = (char*)d_ws;
    bf16* xb   = (bf16*)(ws);                     // 8 MB
    bf16* wbT  = (bf16*)(ws + (8ull << 20));      // 6 MB
    bf16* owbT = (bf16*)(ws + (14ull << 20));     // 2 MB
    bf16* Qb   = (bf16*)(ws + (16ull << 20));     // 8 MB (B,H,T,Dh), pre-scaled
    bf16* Kb   = (bf16*)(ws + (24ull << 20));     // 8 MB (B,H,T,Dh)
    bf16* Vt   = (bf16*)(ws + (32ull << 20));     // 8 MB (B,H,Dh,T)
    bf16* AO   = (bf16*)(ws + (40ull << 20));     // 8 MB (B,T,C)

    prep<<<8192, 256, 0, stream>>>(x, xb, qkv_w, wbT, out_w, owbT);
    gemm_qkv<<<dim3(12, 16), 512, 0, stream>>>(xb, wbT, qkv_b, Qb, Kb, Vt);
    attn<<<1024, 256, 0, stream>>>(Qb, Kb, Vt, AO);
    gemm_out_k<<<dim3(8, 64), 256, 0, stream>>>(AO, owbT, out_b, out);
}

// Round 7
// 175.642 us; speedup vs baseline: 1.0447x; 1.0447x over previous
//
#include <hip/hip_runtime.h>

// Causal MHSA: B=2, T=2048, C=1024, H=16, Dh=64.
// prep -> QKV GEMM -> flash attn (S^T orientation) -> out GEMM.
//
// R18 = R11 restored (the 175.7us known-good kernel) + ONE change:
// prep's weight-transpose stores vectorized (4x scalar 2B bf16 stores ->
// one bf16x4 8B store per thread; LDS read pattern 2 lanes/bank = free).
// The 256x256 8-phase gemm_qkv line (R12-R17) is abandoned: five sync
// treatments all plateaued at 43-46us / MfmaUtil ~20% -> structural
// (1 block/CU, 192/256 CUs, no TLP to hide barriers); R11's 2-barrier
// BK=32 128^2 structure at 3 blocks/CU (m114 implicit overlap) is the
// empirical optimum for this harness. attn (R7) and gemm_out_k unchanged.

typedef __bf16 bf16;
typedef __attribute__((ext_vector_type(4))) __bf16 bf16x4;
typedef __attribute__((ext_vector_type(8))) __bf16 bf16x8;
typedef __attribute__((ext_vector_type(4))) float f32x4;

#define T_SEQ 2048
#define NHEAD 16
#define QSCALE 0.1803368801111244f  // log2(e)/sqrt(64)

__device__ __forceinline__ void async16(const bf16* g, const bf16* l) {
    __builtin_amdgcn_global_load_lds(
        (const __attribute__((address_space(1))) void*)g,
        (__attribute__((address_space(3))) void*)l, 16, 0, 0);
}

// ---------------- fused prep ----------------
__global__ __launch_bounds__(256) void prep(
    const float* __restrict__ x, bf16* __restrict__ xb,
    const float* __restrict__ qkv_w, bf16* __restrict__ wbT,
    const float* __restrict__ out_w, bf16* __restrict__ owbT) {
    const int bid = blockIdx.x, tid = threadIdx.x;
    if (bid < 4096) {
        int i = (bid * 256 + tid) * 4;
        float4 v = *(const float4*)(x + i);
        bf16x4 o;
        o.x = (bf16)v.x; o.y = (bf16)v.y; o.z = (bf16)v.z; o.w = (bf16)v.w;
        *(bf16x4*)(xb + i) = o;
        return;
    }
    __shared__ float tile[32][33];
    const float* in;
    bf16* out;
    int K_, N_, b;
    if (bid < 7168) { b = bid - 4096; in = qkv_w; out = wbT; K_ = 1024; N_ = 3072; }
    else            { b = bid - 7168; in = out_w; out = owbT; K_ = 1024; N_ = 1024; }
    int k0 = (b & 31) * 32, n0 = (b >> 5) * 32;
    int tx = tid & 31, ty = tid >> 5;
    for (int r = 0; r < 32; r += 8)
        tile[ty + r][tx] = in[(k0 + ty + r) * N_ + n0 + tx];
    __syncthreads();
    // vectorized store: thread -> output row rr (n-dim), 4 consecutive k.
    // LDS reads tile[kk+j][rr]: bank = (4*(tid&7) + (tid>>3) + 33j) % 32
    // -> 2 lanes/bank = free (m136). Store 8B aligned bf16x4.
    int rr = tid >> 3, kk = (tid & 7) * 4;
    bf16x4 o4;
    o4[0] = (bf16)tile[kk + 0][rr];
    o4[1] = (bf16)tile[kk + 1][rr];
    o4[2] = (bf16)tile[kk + 2][rr];
    o4[3] = (bf16)tile[kk + 3][rr];
    *(bf16x4*)(out + (n0 + rr) * K_ + k0 + kk) = o4;
}

// ---------------- GEMM 1: qkv = x @ qkv_w + b, scatter to Q/K/Vt ----------------
// 128x128 tile, BK=32, single-buffer two-barrier (R8), fat-row swizzled LDS.
__global__ __launch_bounds__(256) void gemm_qkv(
    const bf16* __restrict__ A, const bf16* __restrict__ Bt,
    const float* __restrict__ bias,
    bf16* __restrict__ Qo, bf16* __restrict__ Ko, bf16* __restrict__ Vt) {
    __shared__ __align__(16) bf16 As[128 * 32];
    __shared__ __align__(16) bf16 Bs[128 * 32];
    const int t = threadIdx.x;
    const int lane = t & 63, wave = t >> 6;
    const int l15 = lane & 15, quad = lane >> 4;
    const int wm = wave & 1, wn = wave >> 1;
    const int m0 = blockIdx.y * 128, n0 = blockIdx.x * 128;
    const int sec = n0 >> 10;  // block-uniform: 0=Q, 1=K, 2=V

    f32x4 acc[4][4] = {};

    // fat-row staging: thread t -> phys granule t (LDS elems t*8), source
    // fat row sfat=t>>3, logical granule slg = (t&7)^(sfat&7):
    // m-row = sfat*2 + (slg>>2), k-offset = (slg&3)*8
    const int sfat = t >> 3, sp = t & 7;
    const int slg = sp ^ (sfat & 7);
    const int smrow = sfat * 2 + (slg >> 2);
    const int skoff = (slg & 3) << 3;
    const bf16* ag = A + (m0 + smrow) * 1024 + skoff;
    const bf16* bg = Bt + (n0 + smrow) * 1024 + skoff;
    bf16* as0 = As + wave * 512;
    bf16* as1 = As + 2048 + wave * 512;
    bf16* bs0 = Bs + wave * 512;
    bf16* bs1 = Bs + 2048 + wave * 512;

    // frag read: row base+l15 -> fat (base/2 + (l15>>1)), phys granule
    // (((l15&1)*4)|quad) ^ (l15>>1); (base*32 + foff) == fat*64 + phys*8
    const int foff = (l15 >> 1) * 64 + (((((l15 & 1) << 2) | quad)) ^ (l15 >> 1)) * 8;

    if (sec < 2) {
        // swapped orientation: acc[j][i] = C^T (row=feature, col=t)
        for (int k0 = 0; k0 < 1024; k0 += 32) {
            async16(ag + k0, as0);
            async16(ag + 64 * 1024 + k0, as1);
            async16(bg + k0, bs0);
            async16(bg + 64 * 1024 + k0, bs1);
            __syncthreads();
            bf16x8 af[4], bfr[4];
            for (int i = 0; i < 4; i++)
                af[i] = *(const bf16x8*)(As + (wm * 64 + i * 16) * 32 + foff);
            for (int j = 0; j < 4; j++)
                bfr[j] = *(const bf16x8*)(Bs + (wn * 64 + j * 16) * 32 + foff);
            for (int j = 0; j < 4; j++)
                for (int i = 0; i < 4; i++)
                    acc[j][i] = __builtin_amdgcn_mfma_f32_16x16x32_bf16(bfr[j], af[i], acc[j][i], 0, 0, 0);
            __syncthreads();
        }
        bf16* dst = (sec == 0) ? Qo : Ko;
        const float sc = (sec == 0) ? QSCALE : 1.0f;
        for (int j = 0; j < 4; j++) {
            int col0 = n0 + wn * 64 + j * 16 + quad * 4;  // 4 consecutive feats
            float4 bv = *(const float4*)(bias + col0);
            int c2 = col0 & 1023, h = c2 >> 6, d0 = c2 & 63;
            for (int i = 0; i < 4; i++) {
                int row = m0 + wm * 64 + i * 16 + l15;
                int b = row >> 11, tt = row & 2047;
                int bh = b * NHEAD + h;
                bf16x4 o;
                o[0] = (bf16)((acc[j][i][0] + bv.x) * sc);
                o[1] = (bf16)((acc[j][i][1] + bv.y) * sc);
                o[2] = (bf16)((acc[j][i][2] + bv.z) * sc);
                o[3] = (bf16)((acc[j][i][3] + bv.w) * sc);
                *(bf16x4*)(dst + (bh * T_SEQ + tt) * 64 + d0) = o;
            }
        }
    } else {
        // normal orientation: acc[i][j] (row=t, col=feature) -> Vt
        for (int k0 = 0; k0 < 1024; k0 += 32) {
            async16(ag + k0, as0);
            async16(ag + 64 * 1024 + k0, as1);
            async16(bg + k0, bs0);
            async16(bg + 64 * 1024 + k0, bs1);
            __syncthreads();
            bf16x8 af[4], bfr[4];
            for (int i = 0; i < 4; i++)
                af[i] = *(const bf16x8*)(As + (wm * 64 + i * 16) * 32 + foff);
            for (int j = 0; j < 4; j++)
                bfr[j] = *(const bf16x8*)(Bs + (wn * 64 + j * 16) * 32 + foff);
            for (int i = 0; i < 4; i++)
                for (int j = 0; j < 4; j++)
                    acc[i][j] = __builtin_amdgcn_mfma_f32_16x16x32_bf16(af[i], bfr[j], acc[i][j], 0, 0, 0);
            __syncthreads();
        }
        for (int j = 0; j < 4; j++) {
            int col = n0 + wn * 64 + j * 16 + l15;
            float bv = bias[col];
            int c2 = col & 1023, h = c2 >> 6, d = c2 & 63;
            for (int i = 0; i < 4; i++) {
                int row0 = m0 + wm * 64 + i * 16 + quad * 4;  // 4 consecutive t
                int b = row0 >> 11, tt0 = row0 & 2047;
                int bh = b * NHEAD + h;
                bf16x4 o;
                for (int r = 0; r < 4; r++)
                    o[r] = (bf16)(acc[i][j][r] + bv);
                *(bf16x4*)(Vt + (bh * 64 + d) * T_SEQ + tt0) = o;
            }
        }
    }
}

// ---------------- attention (R7, unchanged) ----------------
#define PST 80
__global__ __launch_bounds__(256, 4) void attn(
    const bf16* __restrict__ Q, const bf16* __restrict__ K,
    const bf16* __restrict__ Vt, bf16* __restrict__ AO) {
    __shared__ __align__(16) bf16 Ks[2][64 * 64];
    __shared__ __align__(16) bf16 Vs[2][64 * 64];
    __shared__ __align__(16) bf16 Pa[4][16 * PST];
    const int tid = threadIdx.x;
    const int lane = tid & 63, wave = tid >> 6;
    const int l15 = lane & 15, quad = lane >> 4;
    const int xcdr = blockIdx.x & 7;
    const int i_ = blockIdx.x >> 3;
    const int bh = (xcdr << 2) | (i_ & 3);
    const int ti = i_ >> 2;
    const int qt = (ti & 1) ? (ti >> 1) : (31 - (ti >> 1));
    const int t0w = qt * 64 + wave * 16;

    const bf16* kp = K + bh * T_SEQ * 64;
    const bf16* vp = Vt + bh * 64 * T_SEQ;
    bf16* pw = &Pa[wave][0];
    const int b_ = bh >> 4, h_ = bh & 15;

    const int sx = (quad ^ (l15 & 7)) << 3;

    const bf16* qp = Q + (bh * T_SEQ + t0w) * 64;
    bf16x8 qf0 = *(const bf16x8*)(qp + l15 * 64 + quad * 8);
    bf16x8 qf1 = *(const bf16x8*)(qp + l15 * 64 + 32 + quad * 8);

    auto stage = [&](int kb, int b) {
        for (int i = 0; i < 2; i++) {
            int row = i * 32 + (tid >> 3), p = tid & 7;
            const bf16* ksrc = kp + (kb + row) * 64 + ((p ^ (row & 7)) << 3);
            async16(ksrc, &Ks[b][i * 2048 + wave * 512]);
            const bf16* vsrc = vp + row * T_SEQ + kb + ((p ^ (row & 7)) << 3);
            async16(vsrc, &Vs[b][i * 2048 + wave * 512]);
        }
    };

    f32x4 acc[4] = {};
    float lsum = 0.0f;

    const int C = qt + 1;
    stage(0, 0);
    for (int c = 0; c < C; c++) {
        __syncthreads();
        if (c + 1 < C) stage((c + 1) * 64, (c + 1) & 1);
        const bf16* ksb = &Ks[c & 1][0];
        const bf16* vsb = &Vs[c & 1][0];
        const bool dg = (c == qt);
        const int na = dg ? (wave + 1) : 4;

        f32x4 sc[4];
        for (int n = 0; n < 4; n++) {
            if (n < na) {
                const bf16* kbase = ksb + (n * 16 + l15) * 64;
                bf16x8 kf0 = *(const bf16x8*)(kbase + sx);
                bf16x8 kf1 = *(const bf16x8*)(kbase + (sx ^ 32));
                f32x4 z = {};
                z = __builtin_amdgcn_mfma_f32_16x16x32_bf16(kf0, qf0, z, 0, 0, 0);
                z = __builtin_amdgcn_mfma_f32_16x16x32_bf16(kf1, qf1, z, 0, 0, 0);
                sc[n] = z;
            }
        }
        for (int n = 0; n < 4; n++) {
            bf16x4 pv;
            if (n < na) {
                const bool dmask = dg && (n == na - 1);
                for (int r = 0; r < 4; r++) {
                    float v = sc[n][r];
                    if (dmask && (quad * 4 + r > l15)) v = -100000.0f;
                    float e = __builtin_amdgcn_exp2f(v);
                    lsum += e;
                    pv[r] = (bf16)e;
                }
            } else {
                pv[0] = pv[1] = pv[2] = pv[3] = (bf16)0.0f;
            }
            *(bf16x4*)(pw + l15 * PST + n * 16 + quad * 4) = pv;
        }
        __builtin_amdgcn_s_waitcnt(0xC07F);
        for (int g = 0; g < 2; g++) {
            bf16x8 pf = *(const bf16x8*)(pw + l15 * PST + g * 32 + quad * 8);
            for (int j = 0; j < 4; j++) {
                const bf16* vbase = vsb + (j * 16 + l15) * 64;
                bf16x8 vf = *(const bf16x8*)(vbase + (g ? (sx ^ 32) : sx));
                acc[j] = __builtin_amdgcn_mfma_f32_16x16x32_bf16(pf, vf, acc[j], 0, 0, 0);
            }
        }
    }

    lsum += __shfl_xor(lsum, 16);
    lsum += __shfl_xor(lsum, 32);
    float linv = 1.0f / lsum;

    bf16* aop = AO + (b_ * T_SEQ + t0w) * 1024 + h_ * 64;
    for (int r = 0; r < 4; r++) {
        float lr = __shfl(linv, quad * 4 + r, 16);
        for (int j = 0; j < 4; j++)
            aop[(quad * 4 + r) * 1024 + j * 16 + l15] = (bf16)(acc[j][r] * lr);
    }
}

// ---------------- GEMM 2: out = AO @ out_w + out_b (fp32 out) ----------------
// 64x128 tile, BK=32, single-buffer two-barrier, fat-row swizzled LDS.
// 512 blocks (2/CU). C^T orientation -> float4 stores.
__global__ __launch_bounds__(256) void gemm_out_k(
    const bf16* __restrict__ A, const bf16* __restrict__ Bt,
    const float* __restrict__ bias, float* __restrict__ out) {
    __shared__ __align__(16) bf16 As[64 * 32];
    __shared__ __align__(16) bf16 Bs[128 * 32];
    const int t = threadIdx.x;
    const int lane = t & 63, wave = t >> 6;
    const int l15 = lane & 15, quad = lane >> 4;
    const int wm = wave & 1, wn = wave >> 1;
    const int m0 = blockIdx.y * 64, n0 = blockIdx.x * 128;

    f32x4 acc[4][2] = {};  // acc[j][i]: C^T (row=feature, col=t)

    const int sfat = t >> 3, sp = t & 7;
    const int slg = sp ^ (sfat & 7);
    const int smrow = sfat * 2 + (slg >> 2);
    const int skoff = (slg & 3) << 3;
    const bf16* ag = A + (m0 + smrow) * 1024 + skoff;
    const bf16* bg = Bt + (n0 + smrow) * 1024 + skoff;
    bf16* as0 = As + wave * 512;
    bf16* bs0 = Bs + wave * 512;
    bf16* bs1 = Bs + 2048 + wave * 512;

    const int foff = (l15 >> 1) * 64 + (((((l15 & 1) << 2) | quad)) ^ (l15 >> 1)) * 8;

    for (int k0 = 0; k0 < 1024; k0 += 32) {
        async16(ag + k0, as0);
        async16(bg + k0, bs0);
        async16(bg + 64 * 1024 + k0, bs1);
        __syncthreads();
        bf16x8 af[2], bfr[4];
        for (int i = 0; i < 2; i++)
            af[i] = *(const bf16x8*)(As + (wm * 32 + i * 16) * 32 + foff);
        for (int j = 0; j < 4; j++)
            bfr[j] = *(const bf16x8*)(Bs + (wn * 64 + j * 16) * 32 + foff);
        for (int j = 0; j < 4; j++)
            for (int i = 0; i < 2; i++)
                acc[j][i] = __builtin_amdgcn_mfma_f32_16x16x32_bf16(bfr[j], af[i], acc[j][i], 0, 0, 0);
        __syncthreads();
    }

    for (int j = 0; j < 4; j++) {
        int col0 = n0 + wn * 64 + j * 16 + quad * 4;
        float4 bv = *(const float4*)(bias + col0);
        for (int i = 0; i < 2; i++) {
            int row = m0 + wm * 32 + i * 16 + l15;
            float4 o;
            o.x = acc[j][i][0] + bv.x;
            o.y = acc[j][i][1] + bv.y;
            o.z = acc[j][i][2] + bv.z;
            o.w = acc[j][i][3] + bv.w;
            *(float4*)(out + row * 1024 + col0) = o;
        }
    }
}

// ---------------- launch ----------------
extern "C" void kernel_launch(void* const* d_in, const int* in_sizes, int n_in,
                              void* d_out, int out_size, void* d_ws, size_t ws_size,
                              hipStream_t stream) {
    const float* x     = (const float*)d_in[0];
    const float* qkv_w = (const float*)d_in[1];
    const float* qkv_b = (const float*)d_in[2];
    const float* out_w = (const float*)d_in[3];
    const float* out_b = (const float*)d_in[4];
    float* out = (float*)d_out;

    char* ws = (char*)d_ws;
    bf16* xb   = (bf16*)(ws);                     // 8 MB
    bf16* wbT  = (bf16*)(ws + (8ull << 20));      // 6 MB
    bf16* owbT = (bf16*)(ws + (14ull << 20));     // 2 MB
    bf16* Qb   = (bf16*)(ws + (16ull << 20));     // 8 MB (B,H,T,Dh), pre-scaled
    bf16* Kb   = (bf16*)(ws + (24ull << 20));     // 8 MB (B,H,T,Dh)
    bf16* Vt   = (bf16*)(ws + (32ull << 20));     // 8 MB (B,H,Dh,T)
    bf16* AO   = (bf16*)(ws + (40ull << 20));     // 8 MB (B,T,C)

    prep<<<8192, 256, 0, stream>>>(x, xb, qkv_w, wbT, out_w, owbT);
    gemm_qkv<<<dim3(24, 32), 256, 0, stream>>>(xb, wbT, qkv_b, Qb, Kb, Vt);
    attn<<<1024, 256, 0, stream>>>(Qb, Kb, Vt, AO);
    gemm_out_k<<<dim3(8, 64), 256, 0, stream>>>(AO, owbT, out_b, out);
}